// Round 1
// baseline (26851.895 us; speedup 1.0000x reference)
//
#include <hip/hip_runtime.h>
#include <math.h>

// latentODE: T=200, B=1024, D=128, T_OBS=140, L=20, LAT=32, GRU_U=200, UNITS=100
// Batch-parallel structure: each WG owns NB=4 batch elements and runs the full
// sequential recursion privately (no grid sync needed).

#define BB 1024
#define DD 128
#define NB 4
#define NWG 256   // BB/NB

// workspace layout (floats)
#define WS_W1P 0                      // packed [168][600]: rows 0..39 = y-part, 40..167 = x-part; col = g*200+j
#define WS_B1E (168*600)              // [600] ones-folded effective bias
#define WS_W2P (WS_B1E + 600)         // packed [200][120]: col = g*40+j
#define WS_Z   (WS_W2P + 200*120)     // [1024][32] latent z handed to decoder

__global__ __launch_bounds__(256) void prep_kernel(
    const float* __restrict__ uw1, const float* __restrict__ ub1,
    const float* __restrict__ rw1, const float* __restrict__ rb1,
    const float* __restrict__ nw1, const float* __restrict__ nb1,
    const float* __restrict__ uw2, const float* __restrict__ rw2,
    const float* __restrict__ nw2, float* __restrict__ ws)
{
    int tid = blockIdx.x * blockDim.x + threadIdx.x;
    int nth = gridDim.x * blockDim.x;
    for (int idx = tid; idx < 168*600; idx += nth) {
        int k = idx / 600, c = idx - k*600;
        int g = c / 200, j = c - g*200;
        const float* w1 = (g==0) ? uw1 : (g==1) ? rw1 : nw1;
        ws[WS_W1P + idx] = w1[k*200 + j];
    }
    // ones-folding: rows 168..295 of w1 multiply constant 1.0 -> fold into bias
    for (int c = tid; c < 600; c += nth) {
        int g = c / 200, j = c - g*200;
        const float* w1 = (g==0) ? uw1 : (g==1) ? rw1 : nw1;
        const float* b1 = (g==0) ? ub1 : (g==1) ? rb1 : nb1;
        float s = b1[j];
        for (int k = 168; k < 296; ++k) s += w1[k*200 + j];
        ws[WS_B1E + c] = s;
    }
    for (int idx = tid; idx < 200*120; idx += nth) {
        int k = idx / 120, c = idx - k*120;
        int g = c / 40, j = c - g*40;
        const float* w2 = (g==0) ? uw2 : (g==1) ? rw2 : nw2;
        ws[WS_W2P + idx] = w2[k*40 + j];
    }
}

__global__ __launch_bounds__(512) void enc_kernel(
    const float* __restrict__ truth, const float* __restrict__ tg,
    const int*   __restrict__ obs_idx, const float* __restrict__ eps,
    const float* __restrict__ ew1, const float* __restrict__ eb1,
    const float* __restrict__ ew2, const float* __restrict__ eb2,
    const float* __restrict__ ub2, const float* __restrict__ rb2,
    const float* __restrict__ nb2,
    const float* __restrict__ z0w1, const float* __restrict__ z0b1,
    const float* __restrict__ z0w2, const float* __restrict__ z0b2,
    float* __restrict__ ws)
{
    __shared__ __align__(16) float s_ew1[2000];
    __shared__ __align__(16) float s_ew2[2000];
    __shared__ __align__(16) float s_eb1[100];
    __shared__ float s_eb2[20];
    __shared__ __align__(16) float s_b1e[600];
    __shared__ float s_t[200];
    __shared__ int   s_oi[140];
    __shared__ __align__(16) float s_y[NB][40];     // [ym | ys]
    __shared__ __align__(16) float s_ytmp[NB][20];
    __shared__ float s_kacc[NB][20];
    __shared__ __align__(16) float s_hid[NB][100];
    __shared__ __align__(16) float s_yc[NB][168];   // [y(40) | x(128)]
    __shared__ __align__(16) float s_yc2[NB][168];  // [y*r   | x]
    __shared__ __align__(16) float s_hur[NB][400];  // gate hiddens u,r
    __shared__ __align__(16) float s_hn[NB][200];   // gate hidden n
    __shared__ float s_u[NB][40];
    __shared__ float s_r[NB][40];

    const int t0 = threadIdx.x;
    const int b0 = blockIdx.x * NB;
    const float* wsW1 = ws + WS_W1P;
    const float* wsW2 = ws + WS_W2P;

    for (int i = t0; i < 2000; i += 512) { s_ew1[i] = ew1[i]; s_ew2[i] = ew2[i]; }
    for (int i = t0; i < 600;  i += 512) s_b1e[i] = ws[WS_B1E + i];
    for (int i = t0; i < 200;  i += 512) s_t[i] = tg[i];
    for (int i = t0; i < 140;  i += 512) s_oi[i] = obs_idx[i];
    if (t0 < 100) s_eb1[t0] = eb1[t0];
    if (t0 < 20)  s_eb2[t0] = eb2[t0];
    if (t0 < NB*40) s_y[t0/40][t0%40] = 0.f;
    __syncthreads();

    for (int s = 0; s < 140; ++s) {
        const int oi = s_oi[139 - s];
        const float dt = (s == 0) ? 0.f : (s_t[oi] - s_t[s_oi[140 - s]]);

        // ---- RK4 on ym with enc_f (L->100->L tanh MLP) ----
        if (t0 < 80) { int b = t0 / 20, u = t0 - b*20; s_ytmp[b][u] = s_y[b][u]; }
        __syncthreads();
        for (int e = 0; e < 4; ++e) {
            if (t0 < 100) {             // 4-batch tile per thread
                const int u = t0;
                float a0 = s_eb1[u], a1 = a0, a2 = a0, a3 = a0;
                for (int k = 0; k < 20; k += 4) {
                    const float w0 = s_ew1[(k+0)*100+u], w1 = s_ew1[(k+1)*100+u],
                                w2 = s_ew1[(k+2)*100+u], w3 = s_ew1[(k+3)*100+u];
                    float4 y0 = *(const float4*)&s_ytmp[0][k];
                    float4 y1 = *(const float4*)&s_ytmp[1][k];
                    float4 y2 = *(const float4*)&s_ytmp[2][k];
                    float4 y3 = *(const float4*)&s_ytmp[3][k];
                    a0 += w0*y0.x + w1*y0.y + w2*y0.z + w3*y0.w;
                    a1 += w0*y1.x + w1*y1.y + w2*y1.z + w3*y1.w;
                    a2 += w0*y2.x + w1*y2.y + w2*y2.z + w3*y2.w;
                    a3 += w0*y3.x + w1*y3.y + w2*y3.z + w3*y3.w;
                }
                s_hid[0][u] = tanhf(a0); s_hid[1][u] = tanhf(a1);
                s_hid[2][u] = tanhf(a2); s_hid[3][u] = tanhf(a3);
            }
            __syncthreads();
            if (t0 < 80) {
                int b = t0 / 20, u = t0 - b*20;
                float acc = s_eb2[u];
                for (int k = 0; k < 100; k += 4) {
                    float4 hv = *(const float4*)&s_hid[b][k];
                    acc += hv.x * s_ew2[(k+0)*20+u] + hv.y * s_ew2[(k+1)*20+u]
                         + hv.z * s_ew2[(k+2)*20+u] + hv.w * s_ew2[(k+3)*20+u];
                }
                if (e == 0)      { s_kacc[b][u] = acc;      s_ytmp[b][u] = s_y[b][u] + 0.5f*dt*acc; }
                else if (e == 1) { s_kacc[b][u] += 2.f*acc; s_ytmp[b][u] = s_y[b][u] + 0.5f*dt*acc; }
                else if (e == 2) { s_kacc[b][u] += 2.f*acc; s_ytmp[b][u] = s_y[b][u] + dt*acc; }
                else             { s_y[b][u] += (dt/6.f) * (s_kacc[b][u] + acc); }
            }
            __syncthreads();
        }

        // ---- stage x and build yc = [y | x] ----
        { int b = t0 >> 7, d = t0 & 127;
          s_yc[b][40 + d] = truth[((size_t)oi * BB + (b0 + b)) * DD + d]; }
        if (t0 < NB*40) { int b = t0/40, j = t0 - b*40; s_yc[b][j] = s_y[b][j]; }
        __syncthreads();

        // ---- gate hidden for u,r: tanh(yc @ W1 + b1eff) ----
        if (t0 < 400) {
            const float* wcol = wsW1 + t0;            // col = g*200+j
            float a0 = s_b1e[t0], a1 = a0, a2 = a0, a3 = a0;
            for (int k = 0; k < 168; k += 4) {
                const float w0 = wcol[(size_t)(k+0)*600], w1 = wcol[(size_t)(k+1)*600],
                            w2 = wcol[(size_t)(k+2)*600], w3 = wcol[(size_t)(k+3)*600];
                float4 y0 = *(const float4*)&s_yc[0][k];
                float4 y1 = *(const float4*)&s_yc[1][k];
                float4 y2 = *(const float4*)&s_yc[2][k];
                float4 y3 = *(const float4*)&s_yc[3][k];
                a0 += w0*y0.x + w1*y0.y + w2*y0.z + w3*y0.w;
                a1 += w0*y1.x + w1*y1.y + w2*y1.z + w3*y1.w;
                a2 += w0*y2.x + w1*y2.y + w2*y2.z + w3*y2.w;
                a3 += w0*y3.x + w1*y3.y + w2*y3.z + w3*y3.w;
            }
            s_hur[0][t0] = tanhf(a0); s_hur[1][t0] = tanhf(a1);
            s_hur[2][t0] = tanhf(a2); s_hur[3][t0] = tanhf(a3);
        }
        __syncthreads();

        // ---- u,r = sigmoid(hid @ W2 + b2) ----
        if (t0 < 320) {
            int b = t0 / 80, c = t0 - b*80;
            int g = c / 40, j = c - g*40;
            float acc = g ? rb2[j] : ub2[j];
            const float* wcol = wsW2 + g*40 + j;
            const float* h = &s_hur[b][g*200];
            for (int k = 0; k < 200; k += 4) {
                float4 hv = *(const float4*)&h[k];
                acc += hv.x * wcol[(k+0)*120] + hv.y * wcol[(k+1)*120]
                     + hv.z * wcol[(k+2)*120] + hv.w * wcol[(k+3)*120];
            }
            float sg = 1.f / (1.f + expf(-acc));
            if (g) s_r[b][j] = sg; else s_u[b][j] = sg;
        }
        __syncthreads();

        // ---- yc2 = [y*r | x] ----
        for (int idx = t0; idx < NB*168; idx += 512) {
            int b = idx / 168, k = idx - b*168;
            float v = s_yc[b][k];
            if (k < 40) v *= s_r[b][k];
            s_yc2[b][k] = v;
        }
        __syncthreads();

        // ---- gate hidden for n ----
        if (t0 < 200) {
            const float* wcol = wsW1 + 400 + t0;
            float a0 = s_b1e[400 + t0], a1 = a0, a2 = a0, a3 = a0;
            for (int k = 0; k < 168; k += 4) {
                const float w0 = wcol[(size_t)(k+0)*600], w1 = wcol[(size_t)(k+1)*600],
                            w2 = wcol[(size_t)(k+2)*600], w3 = wcol[(size_t)(k+3)*600];
                float4 y0 = *(const float4*)&s_yc2[0][k];
                float4 y1 = *(const float4*)&s_yc2[1][k];
                float4 y2 = *(const float4*)&s_yc2[2][k];
                float4 y3 = *(const float4*)&s_yc2[3][k];
                a0 += w0*y0.x + w1*y0.y + w2*y0.z + w3*y0.w;
                a1 += w0*y1.x + w1*y1.y + w2*y1.z + w3*y1.w;
                a2 += w0*y2.x + w1*y2.y + w2*y2.z + w3*y2.w;
                a3 += w0*y3.x + w1*y3.y + w2*y3.z + w3*y3.w;
            }
            s_hn[0][t0] = tanhf(a0); s_hn[1][t0] = tanhf(a1);
            s_hn[2][t0] = tanhf(a2); s_hn[3][t0] = tanhf(a3);
        }
        __syncthreads();

        // ---- ns = hidn @ W2n + b2n ; state update ----
        if (t0 < 160) {
            int b = t0 / 40, j = t0 - b*40;
            float acc = nb2[j];
            const float* wcol = wsW2 + 80 + j;
            const float* h = &s_hn[b][0];
            for (int k = 0; k < 200; k += 4) {
                float4 hv = *(const float4*)&h[k];
                acc += hv.x * wcol[(k+0)*120] + hv.y * wcol[(k+1)*120]
                     + hv.z * wcol[(k+2)*120] + hv.w * wcol[(k+3)*120];
            }
            float cand = (j < 20) ? acc : fabsf(acc);
            float uu = s_u[b][j];
            s_y[b][j] = (1.f - uu) * cand + uu * s_y[b][j];
        }
        __syncthreads();
    }

    // ---- z0 head: h = tanh(y @ z0w1 + b1) @ z0w2 + b2 ; z = mean + eps*|std| ----
    if (t0 < 400) {
        int b = t0 / 100, u = t0 - b*100;
        float acc = z0b1[u];
        for (int k = 0; k < 40; k += 4) {
            float4 yv = *(const float4*)&s_y[b][k];
            acc += yv.x * z0w1[(k+0)*100+u] + yv.y * z0w1[(k+1)*100+u]
                 + yv.z * z0w1[(k+2)*100+u] + yv.w * z0w1[(k+3)*100+u];
        }
        s_hn[b][u] = tanhf(acc);
    }
    __syncthreads();
    if (t0 < 256) {
        int b = t0 / 64, u = t0 - b*64;
        float acc = z0b2[u];
        for (int k = 0; k < 100; k += 4) {
            float4 hv = *(const float4*)&s_hn[b][k];
            acc += hv.x * z0w2[(k+0)*64+u] + hv.y * z0w2[(k+1)*64+u]
                 + hv.z * z0w2[(k+2)*64+u] + hv.w * z0w2[(k+3)*64+u];
        }
        s_hid[b][u] = acc;
    }
    __syncthreads();
    if (t0 < 128) {
        int b = t0 / 32, i = t0 - b*32;
        int gb = b0 + b;
        float zv = s_hid[b][i] + eps[gb*32 + i] * fabsf(s_hid[b][32 + i]);
        ws[WS_Z + gb*32 + i] = zv;
    }
}

__global__ __launch_bounds__(512) void dec_kernel(
    const float* __restrict__ tg,
    const float* __restrict__ dw1, const float* __restrict__ db1,
    const float* __restrict__ dw2, const float* __restrict__ db2,
    const float* __restrict__ dw3, const float* __restrict__ db3,
    const float* __restrict__ ow,  const float* __restrict__ ob,
    const float* __restrict__ ws,  float* __restrict__ out)
{
    __shared__ __align__(16) float s_dw1[3200];
    __shared__ __align__(16) float s_dw2[10000];
    __shared__ float s_db1[100], s_db2[100], s_db3[32], s_ob[128];
    __shared__ float s_t[200];
    __shared__ __align__(16) float s_z[NB][32];
    __shared__ __align__(16) float s_zt[NB][32];
    __shared__ float s_ka[NB][32];
    __shared__ __align__(16) float s_h1[NB][100];
    __shared__ __align__(16) float s_h2[NB][100];

    const int t0 = threadIdx.x;
    const int b0 = blockIdx.x * NB;
    for (int i = t0; i < 3200;  i += 512) s_dw1[i] = dw1[i];
    for (int i = t0; i < 10000; i += 512) s_dw2[i] = dw2[i];
    if (t0 < 100) { s_db1[t0] = db1[t0]; s_db2[t0] = db2[t0]; }
    if (t0 < 32)  s_db3[t0] = db3[t0];
    if (t0 < 128) s_ob[t0] = ob[t0];
    for (int i = t0; i < 200; i += 512) s_t[i] = tg[i];
    if (t0 < 128) { int b = t0/32, u = t0 & 31; s_z[b][u] = ws[WS_Z + (b0+b)*32 + u]; }
    __syncthreads();

    for (int s = 0; s < 200; ++s) {
        // ---- output projection of sol[s] = current z ----
        { int b = t0 >> 7, d = t0 & 127;
          float acc = s_ob[d];
          for (int k = 0; k < 32; k += 4) {
              float4 zv = *(const float4*)&s_z[b][k];
              acc += zv.x * ow[(k+0)*128+d] + zv.y * ow[(k+1)*128+d]
                   + zv.z * ow[(k+2)*128+d] + zv.w * ow[(k+3)*128+d];
          }
          out[((size_t)(b0+b) * 200 + s) * 128 + d] = acc; }
        if (s == 199) break;
        const float dt = s_t[s+1] - s_t[s];
        if (t0 < 128) { int b = t0/32, u = t0 & 31; s_zt[b][u] = s_z[b][u]; }
        __syncthreads();

        for (int e = 0; e < 4; ++e) {
            if (t0 < 100) {       // h1 = tanh(zt @ dw1 + db1), 4-batch tile
                const int u = t0;
                float a0 = s_db1[u], a1 = a0, a2 = a0, a3 = a0;
                for (int k = 0; k < 32; k += 4) {
                    const float w0 = s_dw1[(k+0)*100+u], w1 = s_dw1[(k+1)*100+u],
                                w2 = s_dw1[(k+2)*100+u], w3 = s_dw1[(k+3)*100+u];
                    float4 z0v = *(const float4*)&s_zt[0][k];
                    float4 z1v = *(const float4*)&s_zt[1][k];
                    float4 z2v = *(const float4*)&s_zt[2][k];
                    float4 z3v = *(const float4*)&s_zt[3][k];
                    a0 += w0*z0v.x + w1*z0v.y + w2*z0v.z + w3*z0v.w;
                    a1 += w0*z1v.x + w1*z1v.y + w2*z1v.z + w3*z1v.w;
                    a2 += w0*z2v.x + w1*z2v.y + w2*z2v.z + w3*z2v.w;
                    a3 += w0*z3v.x + w1*z3v.y + w2*z3v.z + w3*z3v.w;
                }
                s_h1[0][u] = tanhf(a0); s_h1[1][u] = tanhf(a1);
                s_h1[2][u] = tanhf(a2); s_h1[3][u] = tanhf(a3);
            }
            __syncthreads();
            if (t0 < 100) {       // h2 = tanh(h1 @ dw2 + db2)
                const int u = t0;
                float a0 = s_db2[u], a1 = a0, a2 = a0, a3 = a0;
                for (int k = 0; k < 100; k += 4) {
                    const float w0 = s_dw2[(k+0)*100+u], w1 = s_dw2[(k+1)*100+u],
                                w2 = s_dw2[(k+2)*100+u], w3 = s_dw2[(k+3)*100+u];
                    float4 h0 = *(const float4*)&s_h1[0][k];
                    float4 h1v = *(const float4*)&s_h1[1][k];
                    float4 h2v = *(const float4*)&s_h1[2][k];
                    float4 h3 = *(const float4*)&s_h1[3][k];
                    a0 += w0*h0.x + w1*h0.y + w2*h0.z + w3*h0.w;
                    a1 += w0*h1v.x + w1*h1v.y + w2*h1v.z + w3*h1v.w;
                    a2 += w0*h2v.x + w1*h2v.y + w2*h2v.z + w3*h2v.w;
                    a3 += w0*h3.x + w1*h3.y + w2*h3.z + w3*h3.w;
                }
                s_h2[0][u] = tanhf(a0); s_h2[1][u] = tanhf(a1);
                s_h2[2][u] = tanhf(a2); s_h2[3][u] = tanhf(a3);
            }
            __syncthreads();
            if (t0 < 32) {        // k = h2 @ dw3 + db3 ; RK4 combine (thread owns u, all b)
                const int u = t0;
                float a0 = s_db3[u], a1 = a0, a2 = a0, a3 = a0;
                for (int k = 0; k < 100; k += 4) {
                    const float w0 = dw3[(k+0)*32+u], w1 = dw3[(k+1)*32+u],
                                w2 = dw3[(k+2)*32+u], w3 = dw3[(k+3)*32+u];
                    float4 h0 = *(const float4*)&s_h2[0][k];
                    float4 h1v = *(const float4*)&s_h2[1][k];
                    float4 h2v = *(const float4*)&s_h2[2][k];
                    float4 h3 = *(const float4*)&s_h2[3][k];
                    a0 += w0*h0.x + w1*h0.y + w2*h0.z + w3*h0.w;
                    a1 += w0*h1v.x + w1*h1v.y + w2*h1v.z + w3*h1v.w;
                    a2 += w0*h2v.x + w1*h2v.y + w2*h2v.z + w3*h2v.w;
                    a3 += w0*h3.x + w1*h3.y + w2*h3.z + w3*h3.w;
                }
                float kc[NB] = {a0, a1, a2, a3};
                for (int b = 0; b < NB; ++b) {
                    if (e == 0)      { s_ka[b][u] = kc[b];      s_zt[b][u] = s_z[b][u] + 0.5f*dt*kc[b]; }
                    else if (e == 1) { s_ka[b][u] += 2.f*kc[b]; s_zt[b][u] = s_z[b][u] + 0.5f*dt*kc[b]; }
                    else if (e == 2) { s_ka[b][u] += 2.f*kc[b]; s_zt[b][u] = s_z[b][u] + dt*kc[b]; }
                    else             { s_z[b][u] += (dt/6.f) * (s_ka[b][u] + kc[b]); }
                }
            }
            __syncthreads();
        }
    }
}

extern "C" void kernel_launch(void* const* d_in, const int* in_sizes, int n_in,
                              void* d_out, int out_size, void* d_ws, size_t ws_size,
                              hipStream_t stream)
{
    const float* truth = (const float*)d_in[0];
    const float* tg    = (const float*)d_in[1];
    const int*   oi    = (const int*)d_in[2];
    const float* eps   = (const float*)d_in[3];
    const float* ew1   = (const float*)d_in[4];
    const float* eb1   = (const float*)d_in[5];
    const float* ew2   = (const float*)d_in[6];
    const float* eb2   = (const float*)d_in[7];
    const float* uw1   = (const float*)d_in[8];
    const float* ub1   = (const float*)d_in[9];
    const float* uw2   = (const float*)d_in[10];
    const float* ub2   = (const float*)d_in[11];
    const float* rw1   = (const float*)d_in[12];
    const float* rb1   = (const float*)d_in[13];
    const float* rw2   = (const float*)d_in[14];
    const float* rb2   = (const float*)d_in[15];
    const float* nw1   = (const float*)d_in[16];
    const float* nb1   = (const float*)d_in[17];
    const float* nw2   = (const float*)d_in[18];
    const float* nb2   = (const float*)d_in[19];
    const float* z0w1  = (const float*)d_in[20];
    const float* z0b1  = (const float*)d_in[21];
    const float* z0w2  = (const float*)d_in[22];
    const float* z0b2  = (const float*)d_in[23];
    const float* dw1   = (const float*)d_in[24];
    const float* db1   = (const float*)d_in[25];
    const float* dw2   = (const float*)d_in[26];
    const float* db2   = (const float*)d_in[27];
    const float* dw3   = (const float*)d_in[28];
    const float* db3   = (const float*)d_in[29];
    const float* ow    = (const float*)d_in[30];
    const float* ob    = (const float*)d_in[31];
    float* ws  = (float*)d_ws;
    float* out = (float*)d_out;

    prep_kernel<<<dim3(120), dim3(256), 0, stream>>>(
        uw1, ub1, rw1, rb1, nw1, nb1, uw2, rw2, nw2, ws);
    enc_kernel<<<dim3(NWG), dim3(512), 0, stream>>>(
        truth, tg, oi, eps, ew1, eb1, ew2, eb2, ub2, rb2, nb2,
        z0w1, z0b1, z0w2, z0b2, ws);
    dec_kernel<<<dim3(NWG), dim3(512), 0, stream>>>(
        tg, dw1, db1, dw2, db2, dw3, db3, ow, ob, ws, out);
}

// Round 2
// 8326.657 us; speedup vs baseline: 3.2248x; 3.2248x over previous
//
#include <hip/hip_runtime.h>
#include <math.h>

// latentODE: T=200, B=1024, D=128, T_OBS=140, L=20, LAT=32, GRU_U=200, UNITS=100
// R2 structure:
//   prep:       pack W1x -> wpack[128][640], fold ones-rows into b1e[640], pack W1y[40][600]
//   5x { hpre_gemm(chunk):  hpre[s][bblk][p][600] = x @ W1x + b1e   (28 steps/chunk)
//        enc_chunk(chunk):  sequential GRU-ODE on the 40-dim y-part only (weights in regs) }
//   dec_kernel: sequential RK4 decoder, sol -> ws
//   proj_kernel: sol @ out_w + out_b -> out
#define BB 1024
#define DD 128
#define NB 4
#define NWG 256
#define CH 28      // steps per chunk
#define NCH 5

// ws layout (float offsets)
#define WS_WPACK 0                    // [128][640]
#define WS_B1E   81920                // [640]
#define WS_W1Y   82560                // [40][600]
#define WS_Y     106560               // [40][1024] recurrent state between chunks
#define WS_Z     147520               // [1024][32]
#define WS_HPRE  180288               // [28][256][4][600] = 17,203,200 floats
#define WS_SOL   180288               // [200][1024][32] overlays HPRE (dec runs after enc)

__global__ __launch_bounds__(256) void prep_kernel(
    const float* __restrict__ uw1, const float* __restrict__ ub1,
    const float* __restrict__ rw1, const float* __restrict__ rb1,
    const float* __restrict__ nw1, const float* __restrict__ nb1,
    float* __restrict__ ws)
{
    int tid = blockIdx.x * blockDim.x + threadIdx.x;
    int nth = gridDim.x * blockDim.x;
    // wpack[k][j]: x-rows 40..167 of the three W1s, j in [u 0..199 | r 200..399 | n 400..599], pad to 640
    for (int idx = tid; idx < 128 * 640; idx += nth) {
        int k = idx / 640, j = idx - k * 640;
        float v = 0.f;
        if (j < 600) {
            int g = j / 200, jj = j - g * 200;
            const float* w1 = (g == 0) ? uw1 : (g == 1) ? rw1 : nw1;
            v = w1[(40 + k) * 200 + jj];
        }
        ws[WS_WPACK + idx] = v;
    }
    // b1e[j] = b1[j] + sum of ones-rows (168..295)
    for (int j = tid; j < 640; j += nth) {
        float s = 0.f;
        if (j < 600) {
            int g = j / 200, jj = j - g * 200;
            const float* w1 = (g == 0) ? uw1 : (g == 1) ? rw1 : nw1;
            const float* b1 = (g == 0) ? ub1 : (g == 1) ? rb1 : nb1;
            s = b1[jj];
            for (int k = 168; k < 296; ++k) s += w1[k * 200 + jj];
        }
        ws[WS_B1E + j] = s;
    }
    // w1y[k][j]: y-rows 0..39
    for (int idx = tid; idx < 40 * 600; idx += nth) {
        int k = idx / 600, j = idx - k * 600;
        int g = j / 200, jj = j - g * 200;
        const float* w1 = (g == 0) ? uw1 : (g == 1) ? rw1 : nw1;
        ws[WS_W1Y + idx] = w1[k * 200 + jj];
    }
}

// hpre GEMM: per WG: one s, 64 b-rows, 128 j-cols. K=128 in 2 halves.
__global__ __launch_bounds__(256) void hpre_gemm(
    const float* __restrict__ truth, const int* __restrict__ obs_idx,
    const float* __restrict__ ws, float* __restrict__ hpre, int s0)
{
    __shared__ float sx[64][68];    // [b][k-half]
    __shared__ float sw[64][132];   // [k-half][j-tile]
    const int t0 = threadIdx.x;
    const int jt = blockIdx.x % 5;
    const int bt = (blockIdx.x / 5) % 16;
    const int sl = blockIdx.x / 80;
    const int oi = obs_idx[139 - (s0 + sl)];
    const int b0 = bt * 64;
    const float* wpack = ws + WS_WPACK;
    const float* b1e   = ws + WS_B1E;

    const int jj  = t0 & 15;   // j-lane (j = jt*128 + jj + 16m)
    const int bb4 = t0 >> 4;   // b-quad (b = b0 + 4*bb4 + q)
    float acc[8][4];
#pragma unroll
    for (int m = 0; m < 8; ++m)
#pragma unroll
        for (int q = 0; q < 4; ++q) acc[m][q] = 0.f;

    for (int kh = 0; kh < 2; ++kh) {
        __syncthreads();
        // stage x: truth[oi][b0+bb][kh*64 + k] -> sx[bb][k]
        for (int i = t0; i < 64 * 16; i += 256) {
            int bb = i >> 4, kq = i & 15;
            const float4 v = *(const float4*)&truth[((size_t)oi * BB + b0 + bb) * DD + kh * 64 + kq * 4];
            *(float4*)&sx[bb][kq * 4] = v;
        }
        // stage w: wpack[kh*64+kk][jt*128 + j] -> sw[kk][j]
        for (int i = t0; i < 64 * 32; i += 256) {
            int kk = i >> 5, jq = i & 31;
            const float4 v = *(const float4*)&wpack[(kh * 64 + kk) * 640 + jt * 128 + jq * 4];
            *(float4*)&sw[kk][jq * 4] = v;
        }
        __syncthreads();
#pragma unroll 4
        for (int k = 0; k < 64; ++k) {
            float xv[4], wv[8];
#pragma unroll
            for (int q = 0; q < 4; ++q) xv[q] = sx[bb4 * 4 + q][k];
#pragma unroll
            for (int m = 0; m < 8; ++m) wv[m] = sw[k][jj + 16 * m];
#pragma unroll
            for (int m = 0; m < 8; ++m)
#pragma unroll
                for (int q = 0; q < 4; ++q) acc[m][q] += wv[m] * xv[q];
        }
    }
    const int bblk = bt * 16 + bb4;
#pragma unroll
    for (int m = 0; m < 8; ++m) {
        int j = jt * 128 + jj + 16 * m;
        if (j < 600) {
            float be = b1e[j];
#pragma unroll
            for (int q = 0; q < 4; ++q)
                hpre[(size_t)((sl * 256 + bblk) * 4 + q) * 600 + j] = acc[m][q] + be;
        }
    }
}

__global__ __launch_bounds__(512, 2) void enc_chunk(
    const float* __restrict__ tg, const int* __restrict__ obs_idx,
    const float* __restrict__ eps,
    const float* __restrict__ ew1, const float* __restrict__ eb1,
    const float* __restrict__ ew2, const float* __restrict__ eb2,
    const float* __restrict__ uw2, const float* __restrict__ ub2,
    const float* __restrict__ rw2, const float* __restrict__ rb2,
    const float* __restrict__ nw2, const float* __restrict__ nb2,
    const float* __restrict__ z0w1, const float* __restrict__ z0b1,
    const float* __restrict__ z0w2, const float* __restrict__ z0b2,
    float* __restrict__ ws, int s0)
{
    __shared__ float s_t[200];
    __shared__ int   s_oi[140];
    __shared__ __align__(16) float s_y[40][4];     // [k][b]  (rows 16B)
    __shared__ __align__(16) float s_ytmp[4][24];  // [b][k<20]
    __shared__ float s_kacc[4][24];
    __shared__ __align__(16) float s_hid[4][104];
    __shared__ float s_pa[4][20][5];
    __shared__ __align__(16) float s_hur[400][4];
    __shared__ float s_pw[80][4][4];
    __shared__ float s_u[40][4];
    __shared__ __align__(16) float s_yr[40][4];
    __shared__ __align__(16) float s_hn[200][4];
    __shared__ float s_pn[40][4][4];
    __shared__ float s_z0[4][64];

    const int t0 = threadIdx.x;
    const int bblk = blockIdx.x;
    const int b0 = bblk * 4;
    const float* hpre = ws + WS_HPRE;

    // ---- register-resident weights ----
    float rew1[20], rew2[20], rw1y[40], rw2a[50], rA[50];
    float bias_eb1 = 0.f, bias_eb2 = 0.f, bias_ur = 0.f, bias_n = 0.f;
    if (t0 < 400) {
        const int c = t0 % 100;
#pragma unroll
        for (int k = 0; k < 20; ++k) rew1[k] = ew1[k * 100 + c];
        const int c2 = c % 20, q = c / 20;
#pragma unroll
        for (int i = 0; i < 20; ++i) rew2[i] = ew2[(q * 20 + i) * 20 + c2];
        bias_eb1 = eb1[c];
#pragma unroll
        for (int k = 0; k < 40; ++k) rw1y[k] = ws[WS_W1Y + k * 600 + t0];
    }
    if (t0 >= 200 && t0 < 400) {     // rA = W1n-y column
        const int jn = t0 - 200;
#pragma unroll
        for (int k = 0; k < 40; ++k) rA[k] = ws[WS_W1Y + k * 600 + 400 + jn];
    }
    if (t0 < 320) {                  // rw2a = W2-u/r 50-row quarter
        const int ju = t0 % 80, q = t0 / 80;
        const int g = ju / 40, jjn = ju % 40;
        const float* w2 = g ? rw2 : uw2;
#pragma unroll
        for (int i = 0; i < 50; ++i) rw2a[i] = w2[(q * 50 + i) * 40 + jjn];
        const int jur = t0 % 80;     // reduce-role bias
        bias_ur = (jur < 40) ? ub2[jur] : rb2[jur - 40];
    }
    if (t0 < 160) {                  // rA = W2-n 50-row quarter
        const int jn = t0 % 40, q = t0 / 40;
#pragma unroll
        for (int i = 0; i < 50; ++i) rA[i] = nw2[(q * 50 + i) * 40 + jn];
        bias_n = nb2[t0 % 40];
    }
    if (t0 < 80) bias_eb2 = eb2[t0 % 20];

    for (int i = t0; i < 200; i += 512) s_t[i] = tg[i];
    for (int i = t0; i < 140; i += 512) s_oi[i] = obs_idx[i];
    if (t0 < 160) {
        const int k = t0 % 40, b = t0 / 40;
        s_y[k][b] = (s0 == 0) ? 0.f : ws[WS_Y + k * 1024 + b0 + b];
    }
    __syncthreads();

    for (int sl = 0; sl < CH; ++sl) {
        const int s = s0 + sl;
        const int oi = s_oi[139 - s];
        const float dt = (s == 0) ? 0.f : (s_t[oi] - s_t[s_oi[140 - s]]);

        // prefetch hpre for this step (consumed at stages B/C)
        float hp_ur[4], hp_n[4];
        if (t0 < 400) {
#pragma unroll
            for (int p = 0; p < 4; ++p)
                hp_ur[p] = hpre[(size_t)((sl * 256 + bblk) * 4 + p) * 600 + t0];
        }
        if (t0 >= 200 && t0 < 400) {
#pragma unroll
            for (int p = 0; p < 4; ++p)
                hp_n[p] = hpre[(size_t)((sl * 256 + bblk) * 4 + p) * 600 + 400 + (t0 - 200)];
        }

        // ---- RK4 on ym with enc_f ----
#pragma unroll 1
        for (int e = 0; e < 4; ++e) {
            if (t0 < 400) {
                const int b = t0 / 100, c = t0 % 100;
                float acc = bias_eb1;
                if (e == 0) {
#pragma unroll
                    for (int k = 0; k < 20; ++k) acc += s_y[k][b] * rew1[k];
                } else {
#pragma unroll
                    for (int kq = 0; kq < 5; ++kq) {
                        const float4 v = *(const float4*)&s_ytmp[b][kq * 4];
                        acc += v.x * rew1[4 * kq] + v.y * rew1[4 * kq + 1]
                             + v.z * rew1[4 * kq + 2] + v.w * rew1[4 * kq + 3];
                    }
                }
                s_hid[b][c] = tanhf(acc);
            }
            __syncthreads();
            if (t0 < 400) {
                const int b = t0 / 100, c = t0 % 100;
                const int c2 = c % 20, q = c / 20;
                float acc = 0.f;
#pragma unroll
                for (int i = 0; i < 5; ++i) {
                    const float4 v = *(const float4*)&s_hid[b][q * 20 + i * 4];
                    acc += v.x * rew2[4 * i] + v.y * rew2[4 * i + 1]
                         + v.z * rew2[4 * i + 2] + v.w * rew2[4 * i + 3];
                }
                s_pa[b][c2][q] = acc;
            }
            __syncthreads();
            if (t0 < 80) {
                const int b = t0 / 20, c2 = t0 % 20;
                const float kv = bias_eb2 + s_pa[b][c2][0] + s_pa[b][c2][1]
                               + s_pa[b][c2][2] + s_pa[b][c2][3] + s_pa[b][c2][4];
                const float y0 = s_y[c2][b];
                if (e == 0)      { s_kacc[b][c2] = kv;        s_ytmp[b][c2] = y0 + 0.5f * dt * kv; }
                else if (e == 1) { s_kacc[b][c2] += 2.f * kv; s_ytmp[b][c2] = y0 + 0.5f * dt * kv; }
                else if (e == 2) { s_kacc[b][c2] += 2.f * kv; s_ytmp[b][c2] = y0 + dt * kv; }
                else             { s_y[c2][b] = y0 + (dt / 6.f) * (s_kacc[b][c2] + kv); }
            }
            __syncthreads();
        }

        // ---- B: hur[j] = tanh(hpre_ur + y @ W1y) ----
        if (t0 < 400) {
            float a0 = hp_ur[0], a1 = hp_ur[1], a2 = hp_ur[2], a3 = hp_ur[3];
#pragma unroll
            for (int k = 0; k < 40; ++k) {
                const float w = rw1y[k];
                const float4 yv = *(const float4*)&s_y[k][0];
                a0 += w * yv.x; a1 += w * yv.y; a2 += w * yv.z; a3 += w * yv.w;
            }
            float4 o; o.x = tanhf(a0); o.y = tanhf(a1); o.z = tanhf(a2); o.w = tanhf(a3);
            *(float4*)&s_hur[t0][0] = o;
        }
        __syncthreads();
        // ---- BW2 partials: u/r = sigmoid(hur @ W2) ----
        if (t0 < 320) {
            const int ju = t0 % 80, q = t0 / 80;
            const int base = (ju / 40) * 200 + q * 50;
            float a0 = 0.f, a1 = 0.f, a2 = 0.f, a3 = 0.f;
#pragma unroll
            for (int i = 0; i < 50; ++i) {
                const float w = rw2a[i];
                const float4 hv = *(const float4*)&s_hur[base + i][0];
                a0 += w * hv.x; a1 += w * hv.y; a2 += w * hv.z; a3 += w * hv.w;
            }
            s_pw[ju][0][q] = a0; s_pw[ju][1][q] = a1; s_pw[ju][2][q] = a2; s_pw[ju][3][q] = a3;
        }
        __syncthreads();
        // ---- BW2 reduce: sigmoid; write u; write yr = y*r ----
        if (t0 < 320) {
            const int ju = t0 % 80, b = t0 / 80;
            const float v = bias_ur + s_pw[ju][b][0] + s_pw[ju][b][1] + s_pw[ju][b][2] + s_pw[ju][b][3];
            const float sg = 1.f / (1.f + expf(-v));
            if (ju < 40) s_u[ju][b] = sg;
            else { const int k = ju - 40; s_yr[k][b] = s_y[k][b] * sg; }
        }
        __syncthreads();
        // ---- C: hn = tanh(hpre_n + yr @ W1ny) ----
        if (t0 >= 200 && t0 < 400) {
            const int jn = t0 - 200;
            float a0 = hp_n[0], a1 = hp_n[1], a2 = hp_n[2], a3 = hp_n[3];
#pragma unroll
            for (int k = 0; k < 40; ++k) {
                const float w = rA[k];
                const float4 yv = *(const float4*)&s_yr[k][0];
                a0 += w * yv.x; a1 += w * yv.y; a2 += w * yv.z; a3 += w * yv.w;
            }
            float4 o; o.x = tanhf(a0); o.y = tanhf(a1); o.z = tanhf(a2); o.w = tanhf(a3);
            *(float4*)&s_hn[jn][0] = o;
        }
        __syncthreads();
        // ---- D partials: ns = hn @ W2n ----
        if (t0 < 160) {
            const int jn = t0 % 40, q = t0 / 40;
            float a0 = 0.f, a1 = 0.f, a2 = 0.f, a3 = 0.f;
#pragma unroll
            for (int i = 0; i < 50; ++i) {
                const float w = rA[i];
                const float4 hv = *(const float4*)&s_hn[q * 50 + i][0];
                a0 += w * hv.x; a1 += w * hv.y; a2 += w * hv.z; a3 += w * hv.w;
            }
            s_pn[jn][0][q] = a0; s_pn[jn][1][q] = a1; s_pn[jn][2][q] = a2; s_pn[jn][3][q] = a3;
        }
        __syncthreads();
        // ---- D reduce + state update ----
        if (t0 < 160) {
            const int jn = t0 % 40, b = t0 / 40;
            const float v = bias_n + s_pn[jn][b][0] + s_pn[jn][b][1] + s_pn[jn][b][2] + s_pn[jn][b][3];
            const float cand = (jn < 20) ? v : fabsf(v);
            const float uu = s_u[jn][b];
            s_y[jn][b] = (1.f - uu) * cand + uu * s_y[jn][b];
        }
        __syncthreads();
    }

    // ---- z0 head (last chunk only) ----
    if (s0 + CH == 140) {
        if (t0 < 400) {
            const int b = t0 / 100, u = t0 % 100;
            float acc = z0b1[u];
#pragma unroll
            for (int k = 0; k < 40; ++k) acc += s_y[k][b] * z0w1[k * 100 + u];
            s_hid[b][u] = tanhf(acc);
        }
        __syncthreads();
        if (t0 < 256) {
            const int b = t0 / 64, u = t0 % 64;
            float acc = z0b2[u];
#pragma unroll
            for (int kq = 0; kq < 25; ++kq) {
                const float4 hv = *(const float4*)&s_hid[b][kq * 4];
                acc += hv.x * z0w2[(4 * kq) * 64 + u] + hv.y * z0w2[(4 * kq + 1) * 64 + u]
                     + hv.z * z0w2[(4 * kq + 2) * 64 + u] + hv.w * z0w2[(4 * kq + 3) * 64 + u];
            }
            s_z0[b][u] = acc;
        }
        __syncthreads();
        if (t0 < 128) {
            const int b = t0 / 32, i = t0 % 32;
            const int gb = b0 + b;
            ws[WS_Z + gb * 32 + i] = s_z0[b][i] + eps[gb * 32 + i] * fabsf(s_z0[b][32 + i]);
        }
    }
    // ---- store recurrent state ----
    if (t0 < 160) {
        const int k = t0 % 40, b = t0 / 40;
        ws[WS_Y + k * 1024 + b0 + b] = s_y[k][b];
    }
}

__global__ __launch_bounds__(512, 2) void dec_kernel(
    const float* __restrict__ tg,
    const float* __restrict__ dw1, const float* __restrict__ db1,
    const float* __restrict__ dw2, const float* __restrict__ db2,
    const float* __restrict__ dw3, const float* __restrict__ db3,
    float* __restrict__ ws)
{
    __shared__ float s_dw1[32 * 100];
    __shared__ float s_dw3[100 * 32];
    __shared__ float s_t[200];
    __shared__ __align__(16) float s_z[4][32];
    __shared__ __align__(16) float s_zt[4][32];
    __shared__ float s_ka[4][32];
    __shared__ __align__(16) float s_h1[4][104];
    __shared__ __align__(16) float s_h2[4][104];

    const int t0 = threadIdx.x;
    const int b0 = blockIdx.x * 4;
    for (int i = t0; i < 3200; i += 512) { s_dw1[i] = dw1[i]; s_dw3[i] = dw3[i]; }
    for (int i = t0; i < 200; i += 512) s_t[i] = tg[i];

    float rdw2[100];
    float bias1 = 0.f, bias2 = 0.f, bias3 = 0.f;
    if (t0 < 400) {
        const int c = t0 % 100;
#pragma unroll
        for (int k = 0; k < 100; ++k) rdw2[k] = dw2[k * 100 + c];
        bias1 = db1[c]; bias2 = db2[c];
    }
    if (t0 >= 256 && t0 < 384) bias3 = db3[(t0 - 256) % 32];
    if (t0 < 128) {
        const int b = t0 / 32, k = t0 % 32;
        s_z[b][k] = ws[WS_Z + (b0 + b) * 32 + k];
    }
    __syncthreads();

    for (int s = 0; s < 200; ++s) {
        if (t0 < 128) {
            const int b = t0 / 32, k = t0 % 32;
            const float v = s_z[b][k];
            s_zt[b][k] = v;
            ws[WS_SOL + (size_t)(s * 1024 + b0 + b) * 32 + k] = v;
        }
        if (s == 199) break;
        const float dt = s_t[s + 1] - s_t[s];
        __syncthreads();
#pragma unroll 1
        for (int e = 0; e < 4; ++e) {
            if (t0 < 400) {        // h1 = tanh(zt @ dw1 + b1)
                const int b = t0 / 100, c = t0 % 100;
                float acc = bias1;
#pragma unroll
                for (int kq = 0; kq < 8; ++kq) {
                    const float4 zv = *(const float4*)&s_zt[b][kq * 4];
                    acc += zv.x * s_dw1[(4 * kq) * 100 + c] + zv.y * s_dw1[(4 * kq + 1) * 100 + c]
                         + zv.z * s_dw1[(4 * kq + 2) * 100 + c] + zv.w * s_dw1[(4 * kq + 3) * 100 + c];
                }
                s_h1[b][c] = tanhf(acc);
            }
            __syncthreads();
            if (t0 < 400) {        // h2 = tanh(h1 @ dw2 + b2)
                const int b = t0 / 100, c = t0 % 100;
                float acc = bias2;
#pragma unroll
                for (int kq = 0; kq < 25; ++kq) {
                    const float4 hv = *(const float4*)&s_h1[b][kq * 4];
                    acc += hv.x * rdw2[4 * kq] + hv.y * rdw2[4 * kq + 1]
                         + hv.z * rdw2[4 * kq + 2] + hv.w * rdw2[4 * kq + 3];
                }
                s_h2[b][c] = tanhf(acc);
            }
            __syncthreads();
            if (t0 >= 256 && t0 < 384) {   // k = h2 @ dw3 + b3 ; RK4 combine
                const int i = t0 - 256;
                const int c3 = i % 32, b3 = i / 32;
                float acc = bias3;
#pragma unroll
                for (int kq = 0; kq < 25; ++kq) {
                    const float4 hv = *(const float4*)&s_h2[b3][kq * 4];
                    acc += hv.x * s_dw3[(4 * kq) * 32 + c3] + hv.y * s_dw3[(4 * kq + 1) * 32 + c3]
                         + hv.z * s_dw3[(4 * kq + 2) * 32 + c3] + hv.w * s_dw3[(4 * kq + 3) * 32 + c3];
                }
                const float z0v = s_z[b3][c3];
                if (e == 0)      { s_ka[b3][c3] = acc;        s_zt[b3][c3] = z0v + 0.5f * dt * acc; }
                else if (e == 1) { s_ka[b3][c3] += 2.f * acc; s_zt[b3][c3] = z0v + 0.5f * dt * acc; }
                else if (e == 2) { s_ka[b3][c3] += 2.f * acc; s_zt[b3][c3] = z0v + dt * acc; }
                else             { s_z[b3][c3] = z0v + (dt / 6.f) * (s_ka[b3][c3] + acc); }
            }
            __syncthreads();
        }
    }
}

__global__ __launch_bounds__(256) void proj_kernel(
    const float* __restrict__ ow, const float* __restrict__ ob,
    const float* __restrict__ ws, float* __restrict__ out)
{
    const int t0 = threadIdx.x;
    const int d = t0 & 127, half = t0 >> 7;
    float rw[32];
#pragma unroll
    for (int k = 0; k < 32; ++k) rw[k] = ow[k * 128 + d];
    const float bo = ob[d];
    const int sb0 = blockIdx.x * 64 + half * 32;
#pragma unroll 2
    for (int m = 0; m < 32; ++m) {
        const int sb = sb0 + m;
        const int s = sb >> 10, b = sb & 1023;
        const float4* zp = (const float4*)&ws[WS_SOL + (size_t)sb * 32];
        float acc = bo;
#pragma unroll
        for (int kq = 0; kq < 8; ++kq) {
            const float4 zv = zp[kq];
            acc += zv.x * rw[4 * kq] + zv.y * rw[4 * kq + 1]
                 + zv.z * rw[4 * kq + 2] + zv.w * rw[4 * kq + 3];
        }
        out[((size_t)b * 200 + s) * 128 + d] = acc;
    }
}

extern "C" void kernel_launch(void* const* d_in, const int* in_sizes, int n_in,
                              void* d_out, int out_size, void* d_ws, size_t ws_size,
                              hipStream_t stream)
{
    const float* truth = (const float*)d_in[0];
    const float* tg    = (const float*)d_in[1];
    const int*   oi    = (const int*)d_in[2];
    const float* eps   = (const float*)d_in[3];
    const float* ew1   = (const float*)d_in[4];
    const float* eb1   = (const float*)d_in[5];
    const float* ew2   = (const float*)d_in[6];
    const float* eb2   = (const float*)d_in[7];
    const float* uw1   = (const float*)d_in[8];
    const float* ub1   = (const float*)d_in[9];
    const float* uw2   = (const float*)d_in[10];
    const float* ub2   = (const float*)d_in[11];
    const float* rw1   = (const float*)d_in[12];
    const float* rb1   = (const float*)d_in[13];
    const float* rw2   = (const float*)d_in[14];
    const float* rb2   = (const float*)d_in[15];
    const float* nw1   = (const float*)d_in[16];
    const float* nb1   = (const float*)d_in[17];
    const float* nw2   = (const float*)d_in[18];
    const float* nb2   = (const float*)d_in[19];
    const float* z0w1  = (const float*)d_in[20];
    const float* z0b1  = (const float*)d_in[21];
    const float* z0w2  = (const float*)d_in[22];
    const float* z0b2  = (const float*)d_in[23];
    const float* dw1   = (const float*)d_in[24];
    const float* db1   = (const float*)d_in[25];
    const float* dw2   = (const float*)d_in[26];
    const float* db2   = (const float*)d_in[27];
    const float* dw3   = (const float*)d_in[28];
    const float* db3   = (const float*)d_in[29];
    const float* ow    = (const float*)d_in[30];
    const float* ob    = (const float*)d_in[31];
    float* ws  = (float*)d_ws;
    float* out = (float*)d_out;

    prep_kernel<<<dim3(120), dim3(256), 0, stream>>>(uw1, ub1, rw1, rb1, nw1, nb1, ws);
    for (int c = 0; c < NCH; ++c) {
        hpre_gemm<<<dim3(CH * 16 * 5), dim3(256), 0, stream>>>(truth, oi, ws, ws + WS_HPRE, c * CH);
        enc_chunk<<<dim3(NWG), dim3(512), 0, stream>>>(
            tg, oi, eps, ew1, eb1, ew2, eb2, uw2, ub2, rw2, rb2, nw2, nb2,
            z0w1, z0b1, z0w2, z0b2, ws, c * CH);
    }
    dec_kernel<<<dim3(NWG), dim3(512), 0, stream>>>(tg, dw1, db1, dw2, db2, dw3, db3, ws);
    proj_kernel<<<dim3(3200), dim3(256), 0, stream>>>(ow, ob, ws, out);
}

// Round 3
// 4994.531 us; speedup vs baseline: 5.3763x; 1.6672x over previous
//
#include <hip/hip_runtime.h>
#include <math.h>

// latentODE: T=200, B=1024, D=128, T_OBS=140, L=20, LAT=32, GRU_U=200, UNITS=100
// R3: WG=256 (4 waves), launch_bounds(256,1) -> ~450 VGPR budget, weights truly
// register-resident; all LDS b128 with broadcast-safe layouts; dec z-state in regs.
#define BB 1024
#define DD 128
#define NWG 256
#define CH 28
#define NCH 5

// ws layout (float offsets)
#define WS_WPACK 0
#define WS_B1E   81920
#define WS_W1Y   82560
#define WS_Y     106560
#define WS_Z     147520
#define WS_HPRE  180288
#define WS_SOL   180288

__global__ __launch_bounds__(256) void prep_kernel(
    const float* __restrict__ uw1, const float* __restrict__ ub1,
    const float* __restrict__ rw1, const float* __restrict__ rb1,
    const float* __restrict__ nw1, const float* __restrict__ nb1,
    float* __restrict__ ws)
{
    int tid = blockIdx.x * blockDim.x + threadIdx.x;
    int nth = gridDim.x * blockDim.x;
    for (int idx = tid; idx < 128 * 640; idx += nth) {
        int k = idx / 640, j = idx - k * 640;
        float v = 0.f;
        if (j < 600) {
            int g = j / 200, jj = j - g * 200;
            const float* w1 = (g == 0) ? uw1 : (g == 1) ? rw1 : nw1;
            v = w1[(40 + k) * 200 + jj];
        }
        ws[WS_WPACK + idx] = v;
    }
    for (int j = tid; j < 640; j += nth) {
        float s = 0.f;
        if (j < 600) {
            int g = j / 200, jj = j - g * 200;
            const float* w1 = (g == 0) ? uw1 : (g == 1) ? rw1 : nw1;
            const float* b1 = (g == 0) ? ub1 : (g == 1) ? rb1 : nb1;
            s = b1[jj];
            for (int k = 168; k < 296; ++k) s += w1[k * 200 + jj];
        }
        ws[WS_B1E + j] = s;
    }
    for (int idx = tid; idx < 40 * 600; idx += nth) {
        int k = idx / 600, j = idx - k * 600;
        int g = j / 200, jj = j - g * 200;
        const float* w1 = (g == 0) ? uw1 : (g == 1) ? rw1 : nw1;
        ws[WS_W1Y + idx] = w1[k * 200 + jj];
    }
}

__global__ __launch_bounds__(256) void hpre_gemm(
    const float* __restrict__ truth, const int* __restrict__ obs_idx,
    const float* __restrict__ ws, float* __restrict__ hpre, int s0)
{
    __shared__ float sx[64][68];
    __shared__ float sw[64][132];
    const int t0 = threadIdx.x;
    const int jt = blockIdx.x % 5;
    const int bt = (blockIdx.x / 5) % 16;
    const int sl = blockIdx.x / 80;
    const int oi = obs_idx[139 - (s0 + sl)];
    const int b0 = bt * 64;
    const float* wpack = ws + WS_WPACK;
    const float* b1e   = ws + WS_B1E;

    const int jj  = t0 & 15;
    const int bb4 = t0 >> 4;
    float acc[8][4];
#pragma unroll
    for (int m = 0; m < 8; ++m)
#pragma unroll
        for (int q = 0; q < 4; ++q) acc[m][q] = 0.f;

    for (int kh = 0; kh < 2; ++kh) {
        __syncthreads();
        for (int i = t0; i < 64 * 16; i += 256) {
            int bb = i >> 4, kq = i & 15;
            const float4 v = *(const float4*)&truth[((size_t)oi * BB + b0 + bb) * DD + kh * 64 + kq * 4];
            *(float4*)&sx[bb][kq * 4] = v;
        }
        for (int i = t0; i < 64 * 32; i += 256) {
            int kk = i >> 5, jq = i & 31;
            const float4 v = *(const float4*)&wpack[(kh * 64 + kk) * 640 + jt * 128 + jq * 4];
            *(float4*)&sw[kk][jq * 4] = v;
        }
        __syncthreads();
#pragma unroll 4
        for (int k = 0; k < 64; ++k) {
            float xv[4], wv[8];
#pragma unroll
            for (int q = 0; q < 4; ++q) xv[q] = sx[bb4 * 4 + q][k];
#pragma unroll
            for (int m = 0; m < 8; ++m) wv[m] = sw[k][jj + 16 * m];
#pragma unroll
            for (int m = 0; m < 8; ++m)
#pragma unroll
                for (int q = 0; q < 4; ++q) acc[m][q] += wv[m] * xv[q];
        }
    }
    const int bblk = bt * 16 + bb4;
#pragma unroll
    for (int m = 0; m < 8; ++m) {
        int j = jt * 128 + jj + 16 * m;
        if (j < 600) {
            float be = b1e[j];
#pragma unroll
            for (int q = 0; q < 4; ++q)
                hpre[(size_t)((sl * 256 + bblk) * 4 + q) * 600 + j] = acc[m][q] + be;
        }
    }
}

__global__ __launch_bounds__(256, 1) void enc_chunk(
    const float* __restrict__ tg, const int* __restrict__ obs_idx,
    const float* __restrict__ eps,
    const float* __restrict__ ew1, const float* __restrict__ eb1,
    const float* __restrict__ ew2, const float* __restrict__ eb2,
    const float* __restrict__ uw2, const float* __restrict__ ub2,
    const float* __restrict__ rw2, const float* __restrict__ rb2,
    const float* __restrict__ nw2, const float* __restrict__ nb2,
    const float* __restrict__ z0w1, const float* __restrict__ z0b1,
    const float* __restrict__ z0w2, const float* __restrict__ z0b2,
    float* __restrict__ ws, int s0)
{
    __shared__ float s_t[200];
    __shared__ int   s_oi[140];
    __shared__ __align__(16) float s_y[40][4];      // [k][b]
    __shared__ __align__(16) float s_ytmp[20][4];
    __shared__ float s_kacc[20][4];
    __shared__ __align__(16) float s_hid[4][104];   // pads 100..103 = 0
    __shared__ float s_pe[20][4][2];
    __shared__ __align__(16) float s_ew1t[100 * 20];   // [c][k]
    __shared__ __align__(16) float s_w2n[40 * 212];    // [o][k], k>=200 zero
    __shared__ __align__(16) float s_hur[4][416];      // u: [0..207], r: [208..415]
    __shared__ __align__(16) float s_hn[4][208];       // pads 200..207 = 0
    __shared__ float s_pw[80][4][4];
    __shared__ float s_pn[40][4][4];
    __shared__ float s_u[40][4];
    __shared__ __align__(16) float s_yr[40][4];
    __shared__ float s_z0o[4][64];

    const int t0 = threadIdx.x;
    const int bblk = blockIdx.x;
    const int b0 = bblk * 4;
    const float* hpre = ws + WS_HPRE;

    // ---- register weights (roles; worst-case union ~280 VGPR, fits (256,1)) ----
    float rgy[3][40];     // t<200: W1y cols {u_j, r_j, n_j}
    float rew2h[52];      // t<160: RK stage2 K-half
    float rw2q[2][52];    // t<160: W2 u/r quarter, two outs same gate
    float eb1_r = 0.f, eb2_r = 0.f, bur_r = 0.f, bn_r = 0.f;

    if (t0 < 200) {
#pragma unroll
        for (int g = 0; g < 3; ++g)
#pragma unroll
            for (int k = 0; k < 40; ++k)
                rgy[g][k] = ws[WS_W1Y + k * 600 + g * 200 + t0];
    }
    if (t0 < 100) eb1_r = eb1[t0];
    if (t0 < 160) {
        const int c2 = t0 % 20, kh = t0 / 80;
#pragma unroll
        for (int i = 0; i < 52; ++i) {
            const int row = kh * 52 + i;
            rew2h[i] = (row < 100) ? ew2[row * 20 + c2] : 0.f;
        }
    }
    if (t0 < 80) eb2_r = eb2[t0 % 20];
    if (t0 < 160) {
        const int p = t0 % 20, g = (t0 / 20) % 2, kq = t0 / 40;
        const float* w2 = g ? rw2 : uw2;
#pragma unroll
        for (int j = 0; j < 2; ++j)
#pragma unroll
            for (int i = 0; i < 52; ++i) {
                const int row = kq * 52 + i;
                rw2q[j][i] = (row < 200) ? w2[row * 40 + p + 20 * j] : 0.f;
            }
        bur_r = ((t0 % 80) < 40) ? ub2[t0 % 80] : rb2[(t0 % 80) - 40];
        bn_r = nb2[t0 % 40];
    }

    for (int i = t0; i < 2000; i += 256) { int k = i / 100, c = i % 100; s_ew1t[c * 20 + k] = ew1[i]; }
    for (int i = t0; i < 40 * 212; i += 256) { int o = i / 212, k = i % 212; s_w2n[i] = (k < 200) ? nw2[k * 40 + o] : 0.f; }
    for (int i = t0; i < 200; i += 256) s_t[i] = tg[i];
    for (int i = t0; i < 140; i += 256) s_oi[i] = obs_idx[i];
    if (t0 < 160) { int k = t0 % 40, b = t0 / 40; s_y[k][b] = s0 ? ws[WS_Y + k * 1024 + b0 + b] : 0.f; }
    if (t0 < 4) {
#pragma unroll
        for (int i = 0; i < 4; ++i) s_hid[t0][100 + i] = 0.f;
#pragma unroll
        for (int i = 0; i < 8; ++i) { s_hur[t0][200 + i] = 0.f; s_hur[t0][408 + i] = 0.f; s_hn[t0][200 + i] = 0.f; }
    }
    __syncthreads();

    for (int sl = 0; sl < CH; ++sl) {
        const int s = s0 + sl;
        const int oi = s_oi[139 - s];
        const float dt = (s == 0) ? 0.f : (s_t[oi] - s_t[s_oi[140 - s]]);

        float hpu[4], hpr[4], hpn[4];
        if (t0 < 200) {
#pragma unroll
            for (int q = 0; q < 4; ++q) {
                const size_t r = (size_t)((sl * 256 + bblk) * 4 + q) * 600;
                hpu[q] = hpre[r + t0];
                hpr[q] = hpre[r + 200 + t0];
                hpn[q] = hpre[r + 400 + t0];
            }
        }

        // ---- RK4 on ym (enc_f: 20 -> 100 -> 20) ----
#pragma unroll 1
        for (int e = 0; e < 4; ++e) {
            if (t0 < 100) {
                const int c = t0;
                float a[4] = {eb1_r, eb1_r, eb1_r, eb1_r};
#pragma unroll
                for (int i = 0; i < 5; ++i) {
                    const float4 wv = *(const float4*)&s_ew1t[c * 20 + 4 * i];
                    const float wk[4] = {wv.x, wv.y, wv.z, wv.w};
#pragma unroll
                    for (int kk = 0; kk < 4; ++kk) {
                        const int k = 4 * i + kk;
                        const float4 yv = (e == 0) ? *(const float4*)&s_y[k][0]
                                                   : *(const float4*)&s_ytmp[k][0];
                        a[0] += wk[kk] * yv.x; a[1] += wk[kk] * yv.y;
                        a[2] += wk[kk] * yv.z; a[3] += wk[kk] * yv.w;
                    }
                }
#pragma unroll
                for (int b = 0; b < 4; ++b) s_hid[b][c] = tanhf(a[b]);
            }
            __syncthreads();
            if (t0 < 160) {
                const int c2 = t0 % 20, b = (t0 / 20) % 4, kh = t0 / 80;
                float acc = 0.f;
#pragma unroll
                for (int i = 0; i < 13; ++i) {
                    const float4 hv = *(const float4*)&s_hid[b][kh * 52 + 4 * i];
                    acc += hv.x * rew2h[4 * i] + hv.y * rew2h[4 * i + 1]
                         + hv.z * rew2h[4 * i + 2] + hv.w * rew2h[4 * i + 3];
                }
                s_pe[c2][b][kh] = acc;
            }
            __syncthreads();
            if (t0 < 80) {
                const int c2 = t0 % 20, b = t0 / 20;
                const float kv = eb2_r + s_pe[c2][b][0] + s_pe[c2][b][1];
                const float y0 = s_y[c2][b];
                if (e == 0)      { s_kacc[c2][b] = kv;        s_ytmp[c2][b] = y0 + 0.5f * dt * kv; }
                else if (e == 1) { s_kacc[c2][b] += 2.f * kv; s_ytmp[c2][b] = y0 + 0.5f * dt * kv; }
                else if (e == 2) { s_kacc[c2][b] += 2.f * kv; s_ytmp[c2][b] = y0 + dt * kv; }
                else             { s_y[c2][b] = y0 + (dt / 6.f) * (s_kacc[c2][b] + kv); }
            }
            __syncthreads();
        }

        // ---- B: u/r hidden = tanh(hpre + y @ W1y) ----
        if (t0 < 200) {
            float au[4], ar[4];
#pragma unroll
            for (int b = 0; b < 4; ++b) { au[b] = hpu[b]; ar[b] = hpr[b]; }
#pragma unroll
            for (int k = 0; k < 40; ++k) {
                const float4 yv = *(const float4*)&s_y[k][0];
                const float wu = rgy[0][k], wr = rgy[1][k];
                au[0] += wu * yv.x; au[1] += wu * yv.y; au[2] += wu * yv.z; au[3] += wu * yv.w;
                ar[0] += wr * yv.x; ar[1] += wr * yv.y; ar[2] += wr * yv.z; ar[3] += wr * yv.w;
            }
#pragma unroll
            for (int b = 0; b < 4; ++b) {
                s_hur[b][t0] = tanhf(au[b]);
                s_hur[b][208 + t0] = tanhf(ar[b]);
            }
        }
        __syncthreads();

        // ---- W2 u/r partials: (p,g,kq) -> outs {g_p, g_{p+20}}, K-quarter ----
        if (t0 < 160) {
            const int p = t0 % 20, g = (t0 / 20) % 2, kq = t0 / 40;
            const int goff = g * 208;
            float a1[4] = {0.f, 0.f, 0.f, 0.f}, a2[4] = {0.f, 0.f, 0.f, 0.f};
#pragma unroll
            for (int i = 0; i < 13; ++i) {
                const float wa = rw2q[0][4 * i], wb = rw2q[0][4 * i + 1],
                            wc = rw2q[0][4 * i + 2], wd = rw2q[0][4 * i + 3];
                const float we = rw2q[1][4 * i], wf = rw2q[1][4 * i + 1],
                            wg = rw2q[1][4 * i + 2], wh = rw2q[1][4 * i + 3];
#pragma unroll
                for (int b = 0; b < 4; ++b) {
                    const float4 hv = *(const float4*)&s_hur[b][goff + kq * 52 + 4 * i];
                    a1[b] += hv.x * wa + hv.y * wb + hv.z * wc + hv.w * wd;
                    a2[b] += hv.x * we + hv.y * wf + hv.z * wg + hv.w * wh;
                }
            }
            const int o1 = 40 * g + p, o2 = o1 + 20;
#pragma unroll
            for (int b = 0; b < 4; ++b) { s_pw[o1][b][kq] = a1[b]; s_pw[o2][b][kq] = a2[b]; }
        }
        __syncthreads();

        // ---- u/r reduce: sigmoid; u and yr = y*r ----
        if (t0 < 160) {
            const int o = t0 % 80, bp = t0 / 80;
#pragma unroll
            for (int j = 0; j < 2; ++j) {
                const int b = 2 * bp + j;
                const float v = bur_r + s_pw[o][b][0] + s_pw[o][b][1] + s_pw[o][b][2] + s_pw[o][b][3];
                const float sg = 1.f / (1.f + expf(-v));
                if (o < 40) s_u[o][b] = sg;
                else        s_yr[o - 40][b] = s_y[o - 40][b] * sg;
            }
        }
        __syncthreads();

        // ---- C: n hidden = tanh(hpre_n + yr @ W1ny) ----
        if (t0 < 200) {
            float an[4];
#pragma unroll
            for (int b = 0; b < 4; ++b) an[b] = hpn[b];
#pragma unroll
            for (int k = 0; k < 40; ++k) {
                const float4 yv = *(const float4*)&s_yr[k][0];
                const float w = rgy[2][k];
                an[0] += w * yv.x; an[1] += w * yv.y; an[2] += w * yv.z; an[3] += w * yv.w;
            }
#pragma unroll
            for (int b = 0; b < 4; ++b) s_hn[b][t0] = tanhf(an[b]);
        }
        __syncthreads();

        // ---- W2n partials (weights from LDS, stride 212 = 4*odd) ----
        if (t0 < 160) {
            const int o = t0 % 40, kq = t0 / 40;
            float an[4] = {0.f, 0.f, 0.f, 0.f};
#pragma unroll
            for (int i = 0; i < 13; ++i) {
                const float4 wv = *(const float4*)&s_w2n[o * 212 + kq * 52 + 4 * i];
#pragma unroll
                for (int b = 0; b < 4; ++b) {
                    const float4 hv = *(const float4*)&s_hn[b][kq * 52 + 4 * i];
                    an[b] += hv.x * wv.x + hv.y * wv.y + hv.z * wv.z + hv.w * wv.w;
                }
            }
#pragma unroll
            for (int b = 0; b < 4; ++b) s_pn[o][b][kq] = an[b];
        }
        __syncthreads();

        // ---- n reduce + state update ----
        if (t0 < 160) {
            const int o = t0 % 40, b = t0 / 40;
            const float v = bn_r + s_pn[o][b][0] + s_pn[o][b][1] + s_pn[o][b][2] + s_pn[o][b][3];
            const float cand = (o < 20) ? v : fabsf(v);
            const float uu = s_u[o][b];
            s_y[o][b] = (1.f - uu) * cand + uu * s_y[o][b];
        }
        __syncthreads();
    }

    // ---- z0 head (last chunk) ----
    if (s0 + CH == 140) {
        if (t0 < 100) {
            const int c = t0;
            float a[4] = {z0b1[c], z0b1[c], z0b1[c], z0b1[c]};
#pragma unroll
            for (int k = 0; k < 40; ++k) {
                const float4 yv = *(const float4*)&s_y[k][0];
                const float w = z0w1[k * 100 + c];
                a[0] += w * yv.x; a[1] += w * yv.y; a[2] += w * yv.z; a[3] += w * yv.w;
            }
#pragma unroll
            for (int b = 0; b < 4; ++b) s_hid[b][c] = tanhf(a[b]);
        }
        __syncthreads();
        {
            const int b = t0 / 64, u = t0 % 64;
            float acc = z0b2[u];
#pragma unroll
            for (int i = 0; i < 25; ++i) {
                const float4 hv = *(const float4*)&s_hid[b][4 * i];
                acc += hv.x * z0w2[(4 * i) * 64 + u] + hv.y * z0w2[(4 * i + 1) * 64 + u]
                     + hv.z * z0w2[(4 * i + 2) * 64 + u] + hv.w * z0w2[(4 * i + 3) * 64 + u];
            }
            s_z0o[b][u] = acc;
        }
        __syncthreads();
        if (t0 < 128) {
            const int b = t0 / 32, i = t0 % 32;
            const int gb = b0 + b;
            ws[WS_Z + gb * 32 + i] = s_z0o[b][i] + eps[gb * 32 + i] * fabsf(s_z0o[b][32 + i]);
        }
    }
    if (t0 < 160) {
        const int k = t0 % 40, b = t0 / 40;
        ws[WS_Y + k * 1024 + b0 + b] = s_y[k][b];
    }
}

__global__ __launch_bounds__(256, 1) void dec_kernel(
    const float* __restrict__ tg,
    const float* __restrict__ dw1, const float* __restrict__ db1,
    const float* __restrict__ dw2, const float* __restrict__ db2,
    const float* __restrict__ dw3, const float* __restrict__ db3,
    float* __restrict__ ws)
{
    __shared__ float s_t[200];
    __shared__ __align__(16) float s_zt[4][32];     // [b][k]
    __shared__ __align__(16) float s_h1[4][104];    // pads zero
    __shared__ __align__(16) float s_h2[4][104];    // pads zero
    __shared__ float s_p2[100][4][2];

    const int t0 = threadIdx.x;
    const int b0 = blockIdx.x * 4;

    float rdw1[32], rdw2[2][52], rdw3[104];
    float b1r = 0.f, b2r = 0.f, b3r = 0.f;
    if (t0 < 200) {
        const int c = t0 % 100;
#pragma unroll
        for (int k = 0; k < 32; ++k) rdw1[k] = dw1[k * 100 + c];
        b1r = db1[c]; b2r = db2[c];
        const int cp = t0 % 50, kh = (t0 / 50) % 2;
#pragma unroll
        for (int j = 0; j < 2; ++j)
#pragma unroll
            for (int i = 0; i < 52; ++i) {
                const int row = kh * 52 + i;
                rdw2[j][i] = (row < 100) ? dw2[row * 100 + cp + 50 * j] : 0.f;
            }
    }
    if (t0 < 128) {
        const int c3 = t0 % 32;
#pragma unroll
        for (int i = 0; i < 104; ++i) rdw3[i] = (i < 100) ? dw3[i * 32 + c3] : 0.f;
        b3r = db3[c3];
    }
    for (int i = t0; i < 200; i += 256) s_t[i] = tg[i];
    float z_r = 0.f, ka_r = 0.f;
    if (t0 < 128) {
        const int c3 = t0 % 32, b = t0 / 32;
        z_r = ws[WS_Z + (b0 + b) * 32 + c3];
    }
    if (t0 < 16) { s_h1[t0 / 4][100 + t0 % 4] = 0.f; s_h2[t0 / 4][100 + t0 % 4] = 0.f; }
    __syncthreads();

    for (int s = 0; s < 200; ++s) {
        if (t0 < 128) {
            const int c3 = t0 % 32, b = t0 / 32;
            ws[WS_SOL + (size_t)(s * 1024 + b0 + b) * 32 + c3] = z_r;
            s_zt[b][c3] = z_r;
        }
        if (s == 199) break;
        const float dtv = s_t[s + 1] - s_t[s];
        __syncthreads();

#pragma unroll 1
        for (int e = 0; e < 4; ++e) {
            if (t0 < 200) {          // h1 = tanh(zt @ dw1 + b1): (c, 2 batches)
                const int c = t0 % 100, bp = t0 / 100;
                float a0 = b1r, a1 = b1r;
#pragma unroll
                for (int i = 0; i < 8; ++i) {
                    const float4 z0v = *(const float4*)&s_zt[2 * bp][4 * i];
                    const float4 z1v = *(const float4*)&s_zt[2 * bp + 1][4 * i];
                    const float w0 = rdw1[4 * i], w1 = rdw1[4 * i + 1],
                                w2 = rdw1[4 * i + 2], w3 = rdw1[4 * i + 3];
                    a0 += z0v.x * w0 + z0v.y * w1 + z0v.z * w2 + z0v.w * w3;
                    a1 += z1v.x * w0 + z1v.y * w1 + z1v.z * w2 + z1v.w * w3;
                }
                s_h1[2 * bp][c] = tanhf(a0);
                s_h1[2 * bp + 1][c] = tanhf(a1);
            }
            __syncthreads();
            if (t0 < 200) {          // dw2 partials: (2 cols, K-half, 2 batches)
                const int cp = t0 % 50, kh = (t0 / 50) % 2, bp = t0 / 100;
                float a00 = 0.f, a01 = 0.f, a10 = 0.f, a11 = 0.f;
#pragma unroll
                for (int i = 0; i < 13; ++i) {
                    const float4 h0 = *(const float4*)&s_h1[2 * bp][kh * 52 + 4 * i];
                    const float4 h1v = *(const float4*)&s_h1[2 * bp + 1][kh * 52 + 4 * i];
                    const float wa = rdw2[0][4 * i], wb = rdw2[0][4 * i + 1],
                                wc = rdw2[0][4 * i + 2], wd = rdw2[0][4 * i + 3];
                    const float we = rdw2[1][4 * i], wf = rdw2[1][4 * i + 1],
                                wg = rdw2[1][4 * i + 2], wh = rdw2[1][4 * i + 3];
                    a00 += h0.x * wa + h0.y * wb + h0.z * wc + h0.w * wd;
                    a01 += h1v.x * wa + h1v.y * wb + h1v.z * wc + h1v.w * wd;
                    a10 += h0.x * we + h0.y * wf + h0.z * wg + h0.w * wh;
                    a11 += h1v.x * we + h1v.y * wf + h1v.z * wg + h1v.w * wh;
                }
                s_p2[cp][2 * bp][kh] = a00;     s_p2[cp][2 * bp + 1][kh] = a01;
                s_p2[cp + 50][2 * bp][kh] = a10; s_p2[cp + 50][2 * bp + 1][kh] = a11;
            }
            __syncthreads();
            if (t0 < 200) {          // reduce + tanh -> h2
                const int c = t0 % 100, bp = t0 / 100;
#pragma unroll
                for (int j = 0; j < 2; ++j) {
                    const int b = 2 * bp + j;
                    s_h2[b][c] = tanhf(b2r + s_p2[c][b][0] + s_p2[c][b][1]);
                }
            }
            __syncthreads();
            if (t0 < 128) {          // k = h2 @ dw3 + b3; RK combine in registers
                const int c3 = t0 % 32, b = t0 / 32;
                float acc = b3r;
#pragma unroll
                for (int i = 0; i < 26; ++i) {
                    const float4 hv = *(const float4*)&s_h2[b][4 * i];
                    acc += hv.x * rdw3[4 * i] + hv.y * rdw3[4 * i + 1]
                         + hv.z * rdw3[4 * i + 2] + hv.w * rdw3[4 * i + 3];
                }
                if (e == 0)      { ka_r = acc;        s_zt[b][c3] = z_r + 0.5f * dtv * acc; }
                else if (e == 1) { ka_r += 2.f * acc; s_zt[b][c3] = z_r + 0.5f * dtv * acc; }
                else if (e == 2) { ka_r += 2.f * acc; s_zt[b][c3] = z_r + dtv * acc; }
                else             { z_r += (dtv / 6.f) * (ka_r + acc); }
            }
            __syncthreads();
        }
    }
}

__global__ __launch_bounds__(256) void proj_kernel(
    const float* __restrict__ ow, const float* __restrict__ ob,
    const float* __restrict__ ws, float* __restrict__ out)
{
    const int t0 = threadIdx.x;
    const int d = t0 & 127, half = t0 >> 7;
    float rw[32];
#pragma unroll
    for (int k = 0; k < 32; ++k) rw[k] = ow[k * 128 + d];
    const float bo = ob[d];
    const int sb0 = blockIdx.x * 64 + half * 32;
#pragma unroll 2
    for (int m = 0; m < 32; ++m) {
        const int sb = sb0 + m;
        const int s = sb >> 10, b = sb & 1023;
        const float4* zp = (const float4*)&ws[WS_SOL + (size_t)sb * 32];
        float acc = bo;
#pragma unroll
        for (int kq = 0; kq < 8; ++kq) {
            const float4 zv = zp[kq];
            acc += zv.x * rw[4 * kq] + zv.y * rw[4 * kq + 1]
                 + zv.z * rw[4 * kq + 2] + zv.w * rw[4 * kq + 3];
        }
        out[((size_t)b * 200 + s) * 128 + d] = acc;
    }
}

extern "C" void kernel_launch(void* const* d_in, const int* in_sizes, int n_in,
                              void* d_out, int out_size, void* d_ws, size_t ws_size,
                              hipStream_t stream)
{
    const float* truth = (const float*)d_in[0];
    const float* tg    = (const float*)d_in[1];
    const int*   oi    = (const int*)d_in[2];
    const float* eps   = (const float*)d_in[3];
    const float* ew1   = (const float*)d_in[4];
    const float* eb1   = (const float*)d_in[5];
    const float* ew2   = (const float*)d_in[6];
    const float* eb2   = (const float*)d_in[7];
    const float* uw1   = (const float*)d_in[8];
    const float* ub1   = (const float*)d_in[9];
    const float* uw2   = (const float*)d_in[10];
    const float* ub2   = (const float*)d_in[11];
    const float* rw1   = (const float*)d_in[12];
    const float* rb1   = (const float*)d_in[13];
    const float* rw2   = (const float*)d_in[14];
    const float* rb2   = (const float*)d_in[15];
    const float* nw1   = (const float*)d_in[16];
    const float* nb1   = (const float*)d_in[17];
    const float* nw2   = (const float*)d_in[18];
    const float* nb2   = (const float*)d_in[19];
    const float* z0w1  = (const float*)d_in[20];
    const float* z0b1  = (const float*)d_in[21];
    const float* z0w2  = (const float*)d_in[22];
    const float* z0b2  = (const float*)d_in[23];
    const float* dw1   = (const float*)d_in[24];
    const float* db1   = (const float*)d_in[25];
    const float* dw2   = (const float*)d_in[26];
    const float* db2   = (const float*)d_in[27];
    const float* dw3   = (const float*)d_in[28];
    const float* db3   = (const float*)d_in[29];
    const float* ow    = (const float*)d_in[30];
    const float* ob    = (const float*)d_in[31];
    float* ws  = (float*)d_ws;
    float* out = (float*)d_out;

    prep_kernel<<<dim3(120), dim3(256), 0, stream>>>(uw1, ub1, rw1, rb1, nw1, nb1, ws);
    for (int c = 0; c < NCH; ++c) {
        hpre_gemm<<<dim3(CH * 16 * 5), dim3(256), 0, stream>>>(truth, oi, ws, ws + WS_HPRE, c * CH);
        enc_chunk<<<dim3(NWG), dim3(256), 0, stream>>>(
            tg, oi, eps, ew1, eb1, ew2, eb2, uw2, ub2, rw2, rb2, nw2, nb2,
            z0w1, z0b1, z0w2, z0b2, ws, c * CH);
    }
    dec_kernel<<<dim3(NWG), dim3(256), 0, stream>>>(tg, dw1, db1, dw2, db2, dw3, db3, ws);
    proj_kernel<<<dim3(3200), dim3(256), 0, stream>>>(ow, ob, ws, out);
}